// Round 3
// baseline (162.552 us; speedup 1.0000x reference)
//
#include <hip/hip_runtime.h>
#include <math.h>

#define Hh 128
#define Ww 128
#define HW (Hh*Ww)
#define Bn 4
#define Cn 64
#define On 64
#define KP 200                // LDS A-row stride (shorts): 192 data + 8 pad
                              // (==0 mod 8 for 16B ds_read_b128; row stride
                              //  100 dw == 4 mod 32 banks -> 2-way max = free)
#define OMP 66                // padded px stride for sOM (f16), 64 px
#define NBLK 1024             // dcn grid (half-row blocks)

typedef __attribute__((ext_vector_type(8))) short bf16x8;
typedef __attribute__((ext_vector_type(4))) float f32x4;
typedef __attribute__((ext_vector_type(4))) unsigned short u16x4;

// fp32 -> bf16 round-to-nearest-even
static __device__ __forceinline__ unsigned short f2bf(float f) {
    unsigned u = __builtin_bit_cast(unsigned, f);
    u += 0x7FFFu + ((u >> 16) & 1u);
    return (unsigned short)(u >> 16);
}
static __device__ __forceinline__ short f2h(float f) {
    _Float16 h = (_Float16)f;
    return __builtin_bit_cast(short, h);
}
static __device__ __forceinline__ float h2f(short s) {
    return (float)__builtin_bit_cast(_Float16, s);
}

// workspace layout (bytes): xtb(8M) | conv(16M) | part(512K) | ss | owT | dwT
#define XTB_BYTES   ((size_t)Bn*HW*64*2)
#define CONV_BYTES  ((size_t)Bn*On*HW*4)
#define PART_BYTES  ((size_t)128*NBLK*4)

// ---------------------------------------------------------------------------
// Prep: blocks 0..511 = NCHW->NHWC bf16 transpose (one (b,h) row each);
//       blocks 512..727 = weight pack bf16 tap-major [o][tap][c].
// ---------------------------------------------------------------------------
__global__ __launch_bounds__(256) void prep_k(
    const float* __restrict__ x,  const float* __restrict__ ow,
    const float* __restrict__ dw, unsigned* __restrict__ xtb,
    short* __restrict__ owT,      short* __restrict__ dwT)
{
    int blk = blockIdx.x;
    int t = threadIdx.x;
    if (blk < 512) {
        int b = blk >> 7, h = blk & 127;
        __shared__ float sT[64 * 133];
        const float* xp = x + (size_t)b * Cn * HW + (size_t)h * Ww;
#pragma unroll
        for (int it = 0; it < 32; ++it) {
            int idx = t + 256 * it;        // c(6b) | w(7b)
            int c = idx >> 7, w = idx & 127;
            sT[c * 133 + w] = xp[(size_t)c * HW + w];
        }
        __syncthreads();
        unsigned* op = xtb + (size_t)blk * Ww * 32;   // 32 dwords (64 bf16)/px
#pragma unroll
        for (int it = 0; it < 16; ++it) {
            int idx = t + 256 * it;        // w(7b) | cp(5b)
            int w = idx >> 5, cp = idx & 31;
            unsigned lo = f2bf(sT[(2 * cp) * 133 + w]);
            unsigned hi = f2bf(sT[(2 * cp + 1) * 133 + w]);
            op[(size_t)w * 32 + cp] = lo | (hi << 16);
        }
    } else {
        int u = (blk - 512) * 4 + (t >> 6);   // 0..863
        int c = t & 63;
        if (u < 288) {
            int o = u / 9, kk = u % 9;
            float v = (o < 27) ? ow[(size_t)o * 576 + c * 9 + kk] : 0.0f;
            owT[(size_t)u * 64 + c] = (short)f2bf(v);
        } else {
            int u2 = u - 288;
            int o = u2 / 9, kk = u2 % 9;
            dwT[(size_t)u2 * 64 + c] = (short)f2bf(dw[(size_t)o * 576 + c * 9 + kk]);
        }
    }
}

// ---------------------------------------------------------------------------
// Fused: offset-conv GEMM -> per-thread bilinear prep -> sampling fill ->
// DCN GEMM -> conv store + BN stats partials (transposed part).
// Block = HALF-row (64 px), grid 1024, XCD-swizzled. x is bf16 NHWC.
// R3 RESTRUCTURE: wave owns a 16-px QUARTER (rows w_s*16..+16 of sA) and
// ALL o columns (per ks: 1 A-frag + N B-frags + N MFMA). Every LDS
// structure (sA rows, sOMh/prepQ/prepC px-columns) is WAVE-PRIVATE ->
// phases 1-3 are completely BARRIER-FREE (13 syncs -> 1, only the final
// cross-wave stats reduce). Intra-wave write->read visibility via
// s_waitcnt lgkmcnt(0) (wave-scoped; DS ops of one wave are in-order).
// sOMh un-aliased from sA (needed: no barrier separates phases anymore).
// B-frags (owT/dwT) identical across waves+blocks -> L1-hit.
// Accumulation order unchanged -> bit-identical output vs R2.
// CRITICAL #1: no __launch_bounds__ min-waves arg (R3 spill disaster).
// CRITICAL #2: wave id readfirstlane'd (R4 divergent-uniform trap).
// MFMA 16x16x32 bf16 (validated R8-R12):
//   A lane=[m=l15][k=quad*8+j]; B lane=[k=quad*8+j][n=l15];
//   D lane=[row=quad*4+r][col=l15].
// LDS: sA 25600 + sOMh 3588 + prepQ 4608 + prepC 1152 + sred 2048 = 36996 B
//      -> 4 blocks/CU (160K/37K).
// ---------------------------------------------------------------------------
__global__ __launch_bounds__(256) void dcn_fused_k(
    const unsigned* __restrict__ xtb, const short* __restrict__ owT,
    const float* __restrict__ ob,     const short* __restrict__ dwT,
    float* __restrict__ conv,         float* __restrict__ part)
{
    int raw  = blockIdx.x;
    int blk  = ((raw & 7) << 7) | (raw >> 3);   // b(2b) | h(7b) | half(1b)
    int half = blk & 1;
    int h    = (blk >> 1) & 127;
    int b    = blk >> 8;
    int px0  = half * 64;
    int t    = threadIdx.x;
    int lane = t & 63;
    int quad = lane >> 4;
    int l15  = lane & 15;
    int hl   = lane >> 5;          // half-wave index (unit parity in fills)
    int cl   = lane & 31;          // channel-pair index 0..31
    int w_s  = __builtin_amdgcn_readfirstlane(t >> 6);   // 0..3 (SGPR)
    int pxq  = w_s << 4;           // wave's px-quarter base (wave-uniform)

    __shared__ __align__(16) short sA[64 * KP];               // 25600 B (bf16)
    __shared__ __align__(16) short sOMh[27 * OMP + 12];       //  3588 B (f16)
    __shared__ __align__(16) unsigned short prepQ[576 * 4];   //  4608 B {idx,w00,w01,w10}
    __shared__ __align__(16) unsigned short prepC[576];       //  1152 B {w11}
    __shared__ float sredA[4][64], sredB[4][64];              //  2048 B

    const unsigned* xbd = xtb + (size_t)b * HW * 32;               // dword view
    unsigned* sAd = (unsigned*)sA;                                 // row = 100 dw

    // ================= Phase 1: offset conv GEMM (wave: 16 px x 32 o) ====
    f32x4 oacc[2] = {{0,0,0,0},{0,0,0,0}};

    for (int ck = 0; ck < 3; ++ck) {
        int yy = h + ck - 1;
        bool rowok = ((unsigned)yy < (unsigned)Hh);
        // ---- im2col fill of OWN 16 rows: 48 units (3 kkl x 16 px) x 32 dw
#pragma unroll 4
        for (int it = 0; it < 24; ++it) {
            int unit = it * 2 + hl;          // 0..47
            int kkl = unit >> 4, pxl = unit & 15;
            int px = pxq + pxl;
            int xx = px0 + px + kkl - 1;
            bool valid = rowok && ((unsigned)xx < (unsigned)Ww);
            unsigned v = valid ? xbd[(((size_t)yy << 7) + xx) * 32 + cl] : 0u;
            sAd[px * 100 + kkl * 32 + cl] = v;
        }
        asm volatile("s_waitcnt lgkmcnt(0)" ::: "memory");
#pragma unroll
        for (int ks = 0; ks < 6; ++ks) {
            int kk = ck * 3 + (ks >> 1);
            bf16x8 a = *(const bf16x8*)&sA[(pxq + l15) * KP + ks * 32 + quad * 8];
#pragma unroll
            for (int nt = 0; nt < 2; ++nt) {
                bf16x8 bfr = *(const bf16x8*)&owT[((size_t)(nt * 16 + l15) * 9 + kk) * 64
                                                  + (ks & 1) * 32 + quad * 8];
                oacc[nt] = __builtin_amdgcn_mfma_f32_16x16x32_bf16(a, bfr, oacc[nt], 0, 0, 0);
            }
        }
    }
    // ---- D -> sOMh (+bias), f16; own px columns: px = pxq + quad*4 + r
#pragma unroll
    for (int nt = 0; nt < 2; ++nt) {
        int o = nt * 16 + l15;
        if (o < 27) {
            float bias = ob[o];
#pragma unroll
            for (int r = 0; r < 4; ++r)
                sOMh[o * OMP + pxq + (quad << 2) + r] = f2h(oacc[nt][r] + bias);
        }
    }
    asm volatile("s_waitcnt lgkmcnt(0)" ::: "memory");

    // ================= Phase 2: bilinear prep for OWN quarter ============
    // 144 units = tap(9) x px(16); validity factorizes per-axis onto
    // physical rows/cols (yb,yb+1)/(xb,xb+1); corner weight = wr*wc, mask
    // folded into wr. Base idx yb*128+xb; corners {+0,+1,+128,+129} in-bounds.
#pragma unroll
    for (int j = 0; j < 3; ++j) {
        int unit = j * 64 + lane;            // 0..191; active < 144
        if (unit < 144) {
            int kk = unit >> 4, pxl = unit & 15;
            int px = pxq + pxl;
            float ox = h2f((short)sOMh[kk * OMP + px]);
            float oy = h2f((short)sOMh[(9 + kk) * OMP + px]);
            float mr = h2f((short)sOMh[(18 + kk) * OMP + px]);
            float m  = 1.0f / (1.0f + __expf(-mr));
            float py  = (float)(h - 1 + (kk / 3)) + oy;
            float pxf = (float)(px0 + px - 1 + (kk % 3)) + ox;
            float y0f = floorf(py), x0f = floorf(pxf);
            int y0 = (int)y0f, x0 = (int)x0f;
            float wy = py - y0f, wx = pxf - x0f;
            int yb = min(max(y0, 0), Hh - 2);
            int xb = min(max(x0, 0), Ww - 2);
            float wr0 = (yb == y0) ? (1.0f - wy) : ((yb     == y0 + 1) ? wy : 0.0f);
            float wr1 = (yb == y0) ? wy          : ((yb + 1 == y0    ) ? (1.0f - wy) : 0.0f);
            float wc0 = (xb == x0) ? (1.0f - wx) : ((xb     == x0 + 1) ? wx : 0.0f);
            float wc1 = (xb == x0) ? wx          : ((xb + 1 == x0    ) ? (1.0f - wx) : 0.0f);
            wr0 *= m; wr1 *= m;
            int uG = (kk << 6) + px;
            prepQ[uG * 4 + 0] = (unsigned short)(yb * Ww + xb);
            prepQ[uG * 4 + 1] = (unsigned short)f2h(wr0 * wc0);
            prepQ[uG * 4 + 2] = (unsigned short)f2h(wr0 * wc1);
            prepQ[uG * 4 + 3] = (unsigned short)f2h(wr1 * wc0);
            prepC[uG]         = (unsigned short)f2h(wr1 * wc1);
        }
    }
    asm volatile("s_waitcnt lgkmcnt(0)" ::: "memory");

    // ================= Phase 3: sampling fill + DCN GEMM (16 px x 64 o) ==
    // Fill OWN 16 rows: 2 units/iter (half-waves), lane owns a CHANNEL PAIR.
    // Per unit: b64+b16 broadcast ds_read, ONE gather addr chain (+imm/+add),
    // 4 dword loads, 8 FMA, v_cvt_pk_bf16_f32, 1 b32 LDS write.
    f32x4 acc[4] = {{0,0,0,0},{0,0,0,0},{0,0,0,0},{0,0,0,0}};

    for (int ck = 0; ck < 3; ++ck) {
#pragma unroll 4
        for (int it = 0; it < 24; ++it) {
            int unit = it * 2 + hl;          // 0..47
            int kkl = unit >> 4, pxl = unit & 15;
            int px = pxq + pxl;
            int uG = (ck * 3 + kkl) * 64 + px;
            u16x4 q = *(const u16x4*)&prepQ[uG * 4];     // broadcast ds_read_b64
            float w00 = h2f((short)q[1]);
            float w01 = h2f((short)q[2]);
            float w10 = h2f((short)q[3]);
            float w11 = h2f((short)prepC[uG]);           // broadcast ds_read_u16
            const unsigned* p0 = xbd + (size_t)q[0] * 32 + cl;
            unsigned d00 = p0[0];
            unsigned d01 = p0[32];       // col+1  (imm offset 128 B)
            unsigned d10 = p0[4096];     // row+1  (one extra addr)
            unsigned d11 = p0[4128];     // row+1, col+1 (imm offset)
            float v0 = w00 * __builtin_bit_cast(float, d00 << 16)
                     + w01 * __builtin_bit_cast(float, d01 << 16)
                     + w10 * __builtin_bit_cast(float, d10 << 16)
                     + w11 * __builtin_bit_cast(float, d11 << 16);
            float v1 = w00 * __builtin_bit_cast(float, d00 & 0xFFFF0000u)
                     + w01 * __builtin_bit_cast(float, d01 & 0xFFFF0000u)
                     + w10 * __builtin_bit_cast(float, d10 & 0xFFFF0000u)
                     + w11 * __builtin_bit_cast(float, d11 & 0xFFFF0000u);
            unsigned pk;
            asm("v_cvt_pk_bf16_f32 %0, %1, %2" : "=v"(pk) : "v"(v0), "v"(v1));
            sAd[px * 100 + kkl * 32 + cl] = pk;
        }
        asm volatile("s_waitcnt lgkmcnt(0)" ::: "memory");
#pragma unroll
        for (int ks = 0; ks < 6; ++ks) {
            int kk = ck * 3 + (ks >> 1);
            bf16x8 a = *(const bf16x8*)&sA[(pxq + l15) * KP + ks * 32 + quad * 8];
#pragma unroll
            for (int nt = 0; nt < 4; ++nt) {
                bf16x8 bfr = *(const bf16x8*)&dwT[((size_t)(nt * 16 + l15) * 9 + kk) * 64
                                                  + (ks & 1) * 32 + quad * 8];
                acc[nt] = __builtin_amdgcn_mfma_f32_16x16x32_bf16(a, bfr, acc[nt], 0, 0, 0);
            }
        }
    }

    // ================= Phase 4: store conv + stats partials =================
    // D: row = own px (pxq + quad*4 + r), col = o (nt*16 + l15).
#pragma unroll
    for (int nt = 0; nt < 4; ++nt) {
        int o = nt * 16 + l15;
        size_t idx = ((size_t)b * On + o) * HW + (size_t)h * Ww + px0 + pxq + (quad << 2);
        *(f32x4*)(conv + idx) = acc[nt];
    }
    // per-o sums over own 16 px, then cross-wave reduce via LDS (1 barrier)
#pragma unroll
    for (int nt = 0; nt < 4; ++nt) {
        float s1 = acc[nt][0] + acc[nt][1] + acc[nt][2] + acc[nt][3];
        float s2 = acc[nt][0] * acc[nt][0] + acc[nt][1] * acc[nt][1]
                 + acc[nt][2] * acc[nt][2] + acc[nt][3] * acc[nt][3];
        s1 += __shfl_down(s1, 32, 64);  s2 += __shfl_down(s2, 32, 64);
        s1 += __shfl_down(s1, 16, 64);  s2 += __shfl_down(s2, 16, 64);
        if (lane < 16) {
            sredA[w_s][nt * 16 + lane] = s1;
            sredB[w_s][nt * 16 + lane] = s2;
        }
    }
    __syncthreads();
    if (t < 64) {
        float S1 = sredA[0][t] + sredA[1][t] + sredA[2][t] + sredA[3][t];
        float S2 = sredB[0][t] + sredB[1][t] + sredB[2][t] + sredB[3][t];
        part[(size_t)t * NBLK + blk]        = S1;
        part[(size_t)(64 + t) * NBLK + blk] = S2;
    }
}

// ---------------------------------------------------------------------------
// Fused BN stats + apply + ReLU.
// Grid 1024: o = idx&63, bq = idx>>6. Each block re-reduces its channel's
// part rows (8 KB, L2-hit) -> sc/sh, then applies BN+ReLU over a 4096-float
// slab of conv.
// ---------------------------------------------------------------------------
__global__ __launch_bounds__(256) void bnstats_k(
    const float* __restrict__ part, const float* __restrict__ gamma,
    const float* __restrict__ beta, const float* __restrict__ conv,
    float* __restrict__ out)
{
    int idx = blockIdx.x;
    int o  = idx & 63;
    int bq = idx >> 6;          // b = bq>>2, q = bq&3
    int t = threadIdx.x;
    float s1 = 0.0f, s2 = 0.0f;
#pragma unroll
    for (int i = 0; i < NBLK / 256; ++i) {
        int j = t + 256 * i;
        s1 += part[(size_t)o * NBLK + j];
        s2 += part[(size_t)(64 + o) * NBLK + j];
    }
#pragma unroll
    for (int off = 32; off > 0; off >>= 1) {
        s1 += __shfl_down(s1, off, 64);
        s2 += __shfl_down(s2, off, 64);
    }
    __shared__ float r1[4], r2[4];
    __shared__ float sc_s, sh_s;
    if ((t & 63) == 0) { r1[t >> 6] = s1; r2[t >> 6] = s2; }
    __syncthreads();
    if (t == 0) {
        float S1 = r1[0] + r1[1] + r1[2] + r1[3];
        float S2 = r2[0] + r2[1] + r2[2] + r2[3];
        float n = (float)(Bn * HW);
        float mu = S1 / n;
        float var = S2 / n - mu * mu;
        float sc = gamma[o] * rsqrtf(var + 1e-5f);
        sc_s = sc;
        sh_s = beta[o] - mu * sc;
    }
    __syncthreads();
    float sc = sc_s, sh = sh_s;
    size_t base = (((size_t)(bq >> 2) * On + o) * HW + (size_t)(bq & 3) * 4096) / 4;
    const float4* cv = (const float4*)conv + base;
    float4* ov = (float4*)out + base;
#pragma unroll
    for (int i = 0; i < 4; ++i) {
        float4 v = cv[t + 256 * i];
        v.x = fmaxf(v.x * sc + sh, 0.0f);
        v.y = fmaxf(v.y * sc + sh, 0.0f);
        v.z = fmaxf(v.z * sc + sh, 0.0f);
        v.w = fmaxf(v.w * sc + sh, 0.0f);
        ov[t + 256 * i] = v;
    }
}

// ---------------------------------------------------------------------------
extern "C" void kernel_launch(void* const* d_in, const int* in_sizes, int n_in,
                              void* d_out, int out_size, void* d_ws, size_t ws_size,
                              hipStream_t stream)
{
    const float* x     = (const float*)d_in[0];
    const float* ow    = (const float*)d_in[1];
    const float* ob    = (const float*)d_in[2];
    const float* dw    = (const float*)d_in[3];
    // d_in[4] = dcn_b: cancels exactly under BN mean subtraction -> unused
    const float* gamma = (const float*)d_in[5];
    const float* beta  = (const float*)d_in[6];

    char* wsb = (char*)d_ws;
    unsigned* xtb = (unsigned*)wsb;
    float* conv = (float*)(wsb + XTB_BYTES);
    float* part = (float*)(wsb + XTB_BYTES + CONV_BYTES);
    short* owT  = (short*)(wsb + XTB_BYTES + CONV_BYTES + PART_BYTES + 512);
    short* dwT  = owT + 288 * 64;

    prep_k     <<<dim3(728),  dim3(256), 0, stream>>>(x, ow, dw, xtb, owT, dwT);
    dcn_fused_k<<<dim3(NBLK), dim3(256), 0, stream>>>(xtb, owT, ob, dwT, conv, part);
    bnstats_k  <<<dim3(1024), dim3(256), 0, stream>>>(part, gamma, beta, conv, (float*)d_out);
}

// Round 4
// 131.624 us; speedup vs baseline: 1.2350x; 1.2350x over previous
//
#include <hip/hip_runtime.h>
#include <math.h>

#define Hh 128
#define Ww 128
#define HW (Hh*Ww)
#define Bn 4
#define Cn 64
#define On 64
#define KP 200                // LDS A-row stride (shorts): 192 data + 8 pad
                              // (==0 mod 8 for 16B ds_read_b128; row stride
                              //  100 dw == 4 mod 32 banks -> 2-way max = free)
#define OMP 66                // padded px stride for sOM (f16), 64 px
#define NBLK 1024             // dcn grid (half-row blocks)

typedef __attribute__((ext_vector_type(8))) short bf16x8;
typedef __attribute__((ext_vector_type(4))) float f32x4;
typedef __attribute__((ext_vector_type(4))) unsigned short u16x4;
typedef __attribute__((ext_vector_type(2))) unsigned u32x2;
typedef __attribute__((ext_vector_type(4))) unsigned u32x4;

// fp32 -> bf16 round-to-nearest-even
static __device__ __forceinline__ unsigned short f2bf(float f) {
    unsigned u = __builtin_bit_cast(unsigned, f);
    u += 0x7FFFu + ((u >> 16) & 1u);
    return (unsigned short)(u >> 16);
}
static __device__ __forceinline__ short f2h(float f) {
    _Float16 h = (_Float16)f;
    return __builtin_bit_cast(short, h);
}
static __device__ __forceinline__ float h2f(short s) {
    return (float)__builtin_bit_cast(_Float16, s);
}
static __device__ __forceinline__ float bflo(unsigned d) {
    return __builtin_bit_cast(float, d << 16);
}
static __device__ __forceinline__ float bfhi(unsigned d) {
    return __builtin_bit_cast(float, d & 0xFFFF0000u);
}

// workspace layout (bytes): xtb(8M) | conv(16M) | part(512K) | ss | owT | dwT
#define XTB_BYTES   ((size_t)Bn*HW*64*2)
#define CONV_BYTES  ((size_t)Bn*On*HW*4)
#define PART_BYTES  ((size_t)128*NBLK*4)

// ---------------------------------------------------------------------------
// Prep: blocks 0..511 = NCHW->NHWC bf16 transpose (one (b,h) row each);
//       blocks 512..727 = weight pack bf16 tap-major [o][tap][c].
// ---------------------------------------------------------------------------
__global__ __launch_bounds__(256) void prep_k(
    const float* __restrict__ x,  const float* __restrict__ ow,
    const float* __restrict__ dw, unsigned* __restrict__ xtb,
    short* __restrict__ owT,      short* __restrict__ dwT)
{
    int blk = blockIdx.x;
    int t = threadIdx.x;
    if (blk < 512) {
        int b = blk >> 7, h = blk & 127;
        __shared__ float sT[64 * 133];
        const float* xp = x + (size_t)b * Cn * HW + (size_t)h * Ww;
#pragma unroll
        for (int it = 0; it < 32; ++it) {
            int idx = t + 256 * it;        // c(6b) | w(7b)
            int c = idx >> 7, w = idx & 127;
            sT[c * 133 + w] = xp[(size_t)c * HW + w];
        }
        __syncthreads();
        unsigned* op = xtb + (size_t)blk * Ww * 32;   // 32 dwords (64 bf16)/px
#pragma unroll
        for (int it = 0; it < 16; ++it) {
            int idx = t + 256 * it;        // w(7b) | cp(5b)
            int w = idx >> 5, cp = idx & 31;
            unsigned lo = f2bf(sT[(2 * cp) * 133 + w]);
            unsigned hi = f2bf(sT[(2 * cp + 1) * 133 + w]);
            op[(size_t)w * 32 + cp] = lo | (hi << 16);
        }
    } else {
        int u = (blk - 512) * 4 + (t >> 6);   // 0..863
        int c = t & 63;
        if (u < 288) {
            int o = u / 9, kk = u % 9;
            float v = (o < 27) ? ow[(size_t)o * 576 + c * 9 + kk] : 0.0f;
            owT[(size_t)u * 64 + c] = (short)f2bf(v);
        } else {
            int u2 = u - 288;
            int o = u2 / 9, kk = u2 % 9;
            dwT[(size_t)u2 * 64 + c] = (short)f2bf(dw[(size_t)o * 576 + c * 9 + kk]);
        }
    }
}

// ---------------------------------------------------------------------------
// Fused: offset-conv GEMM -> per-thread bilinear prep -> sampling fill ->
// DCN GEMM -> conv store + BN stats partials (transposed part).
// Block = HALF-row (64 px), grid 1024, XCD-swizzled. x is bf16 NHWC.
// Structure = R2 (13 barriers, wave owns o-tile in GEMMs). R3's barrier-free
// wave-private flip REGRESSED 54->81 us: per-ks global B-frag loads exposed
// ~200cy L1/L2 latency on the MFMA path (compiler can't hoist 24x16B=96
// VGPR). B-operands must stream 1-per-step; A from LDS. DO NOT re-flip.
// R4 (this round): WIDER FILL LOADS, structure untouched.
//  * phase-3 gather: lane owns 4 channels, dwordx2 per corner (128B/corner
//    coalescing kept) -> vmem count 96->48 per wave per ck, iters 24->12.
//  * phase-1 im2col: dwordx4 per lane, 8 lanes/unit -> 24->6 loads/ck.
// Per-channel FMA order unchanged -> bit-identical conv output vs R2.
// CRITICAL #1: no __launch_bounds__ min-waves arg (R3 spill disaster).
// CRITICAL #2: wave id readfirstlane'd (R4 divergent-uniform trap).
// MFMA 16x16x32 bf16 (validated R8-R12):
//   A lane=[m=l15][k=quad*8+j]; B lane=[k=quad*8+j][n=l15];
//   D lane=[row=quad*4+r][col=l15].
// LDS: sA 25600 (sOMh 3588 aliased in) + prepQ 4608 + prepC 1152 = 31360 B.
// ---------------------------------------------------------------------------
__global__ __launch_bounds__(256) void dcn_fused_k(
    const unsigned* __restrict__ xtb, const short* __restrict__ owT,
    const float* __restrict__ ob,     const short* __restrict__ dwT,
    float* __restrict__ conv,         float* __restrict__ part)
{
    int raw  = blockIdx.x;
    int blk  = ((raw & 7) << 7) | (raw >> 3);   // b(2b) | h(7b) | half(1b)
    int half = blk & 1;
    int h    = (blk >> 1) & 127;
    int b    = blk >> 8;
    int px0  = half * 64;
    int t    = threadIdx.x;
    int lane = t & 63;
    int quad = lane >> 4;
    int l15  = lane & 15;
    int qw   = lane >> 4;          // quarter-wave unit id (phase 3 fill)
    int cl2  = lane & 15;          // dword-PAIR (4-channel) index, phase 3
    int og   = lane >> 3;          // eighth-wave unit id (phase 1 fill)
    int li   = lane & 7;           // dwordx4 lane, phase 1
    int w_s  = __builtin_amdgcn_readfirstlane(t >> 6);   // 0..3 (SGPR)

    __shared__ __align__(16) short sA[64 * KP];               // 25600 B (bf16)
    __shared__ __align__(16) unsigned short prepQ[576 * 4];   //  4608 B {idx,w00,w01,w10}
    __shared__ __align__(16) unsigned short prepC[576];       //  1152 B {w11}
    short* sOMh = sA;   // 27*OMP+12 = 1794 shorts, aliased (sA dead in phase 2)

    const unsigned* xbd = xtb + (size_t)b * HW * 32;               // dword view
    unsigned* sAd = (unsigned*)sA;                                 // row = 100 dw

    // ================= Phase 1: offset conv GEMM (M=64, N=32) ============
    int nt_o = w_s & 1;
    int mh   = w_s >> 1;
    int o_ow = nt_o * 16 + l15;
    f32x4 oacc[2] = {{0,0,0,0},{0,0,0,0}};

    for (int ck = 0; ck < 3; ++ck) {
        int yy = h + ck - 1;
        bool rowok = ((unsigned)yy < (unsigned)Hh);
        // ---- im2col fill: 192 units (kkl(2b)|px(6b)), 8 lanes x dwordx4 each
#pragma unroll
        for (int it = 0; it < 6; ++it) {
            int unit = (it * 4 + w_s) * 8 + og;   // 0..191
            int kkl = unit >> 6, px = unit & 63;
            int xx = px0 + px + kkl - 1;
            bool valid = rowok && ((unsigned)xx < (unsigned)Ww);
            u32x4 v = {0u, 0u, 0u, 0u};
            if (valid)
                v = *(const u32x4*)&xbd[(((size_t)yy << 7) + xx) * 32 + li * 4];
            *(u32x4*)&sAd[px * 100 + kkl * 32 + li * 4] = v;
        }
        __syncthreads();
#pragma unroll
        for (int ks = 0; ks < 6; ++ks) {
            int kk = ck * 3 + (ks >> 1);
            bf16x8 bfr = *(const bf16x8*)&owT[((size_t)o_ow * 9 + kk) * 64
                                             + (ks & 1) * 32 + quad * 8];
#pragma unroll
            for (int m2 = 0; m2 < 2; ++m2) {
                bf16x8 a = *(const bf16x8*)&sA[(mh * 32 + m2 * 16 + l15) * KP
                                               + ks * 32 + quad * 8];
                oacc[m2] = __builtin_amdgcn_mfma_f32_16x16x32_bf16(a, bfr, oacc[m2], 0, 0, 0);
            }
        }
        __syncthreads();
    }
    // ---- D -> sOMh (+bias), f16; px = (mh*2+m2)*16 + quad*4 + r
    // (sA is dead here: last chunk's MFMAs completed before the final sync)
    if (o_ow < 27) {
        float bias = ob[o_ow];
#pragma unroll
        for (int m2 = 0; m2 < 2; ++m2) {
            int pxb = (mh * 2 + m2) * 16 + quad * 4;
#pragma unroll
            for (int r = 0; r < 4; ++r)
                sOMh[o_ow * OMP + pxb + r] = f2h(oacc[m2][r] + bias);
        }
    }
    __syncthreads();

    // ================= Phase 2: per-thread bilinear prep -> LDS ==========
    // 576 units = tap(9) x px(64); thread owns u = t, t+256, t+512(<576).
    // Validity factorizes per-axis onto physical rows/cols (yb,yb+1)/(xb,xb+1);
    // corner weight = wr*wc, sigmoid mask folded into wr. Base idx yb*128+xb;
    // corners {+0,+1,+128,+129} always in-bounds.
#pragma unroll
    for (int i = 0; i < 3; ++i) {
        int u = t + 256 * i;
        if (u < 576) {
            int kk = u >> 6, px = u & 63;
            float ox = h2f((short)sOMh[kk * OMP + px]);
            float oy = h2f((short)sOMh[(9 + kk) * OMP + px]);
            float mr = h2f((short)sOMh[(18 + kk) * OMP + px]);
            float m  = 1.0f / (1.0f + __expf(-mr));
            float py  = (float)(h - 1 + (kk / 3)) + oy;
            float pxf = (float)(px0 + px - 1 + (kk % 3)) + ox;
            float y0f = floorf(py), x0f = floorf(pxf);
            int y0 = (int)y0f, x0 = (int)x0f;
            float wy = py - y0f, wx = pxf - x0f;
            int yb = min(max(y0, 0), Hh - 2);
            int xb = min(max(x0, 0), Ww - 2);
            float wr0 = (yb == y0) ? (1.0f - wy) : ((yb     == y0 + 1) ? wy : 0.0f);
            float wr1 = (yb == y0) ? wy          : ((yb + 1 == y0    ) ? (1.0f - wy) : 0.0f);
            float wc0 = (xb == x0) ? (1.0f - wx) : ((xb     == x0 + 1) ? wx : 0.0f);
            float wc1 = (xb == x0) ? wx          : ((xb + 1 == x0    ) ? (1.0f - wx) : 0.0f);
            wr0 *= m; wr1 *= m;
            prepQ[u * 4 + 0] = (unsigned short)(yb * Ww + xb);
            prepQ[u * 4 + 1] = (unsigned short)f2h(wr0 * wc0);
            prepQ[u * 4 + 2] = (unsigned short)f2h(wr0 * wc1);
            prepQ[u * 4 + 3] = (unsigned short)f2h(wr1 * wc0);
            prepC[u]         = (unsigned short)f2h(wr1 * wc1);
        }
    }
    __syncthreads();

    // ================= Phase 3: sampling fill + DCN GEMM (M=64, N=64) ====
    // Fill: 4 units per wave-iter (quarter-waves); lane owns 4 CHANNELS
    // (dword pair). Per unit: b64+b16 broadcast ds_read, ONE gather addr
    // chain, 4x dwordx2 loads (128B/corner coalesced), 16 FMA, 2x
    // v_cvt_pk_bf16_f32, 1 ds_write_b64.
    int o_dw = w_s * 16 + l15;
    f32x4 acc[4] = {{0,0,0,0},{0,0,0,0},{0,0,0,0},{0,0,0,0}};

    for (int ck = 0; ck < 3; ++ck) {
#pragma unroll 4
        for (int it = 0; it < 12; ++it) {
            int unit = (it * 4 + w_s) * 4 + qw;   // 0..191 within ck
            int kkl = unit >> 6, px = unit & 63;
            int uG = (ck * 3 + kkl) * 64 + px;    // global unit id
            u16x4 q = *(const u16x4*)&prepQ[uG * 4];     // broadcast ds_read_b64
            float w00 = h2f((short)q[1]);
            float w01 = h2f((short)q[2]);
            float w10 = h2f((short)q[3]);
            float w11 = h2f((short)prepC[uG]);           // broadcast ds_read_u16
            const unsigned* p0 = xbd + (size_t)q[0] * 32 + cl2 * 2;
            u32x2 d00 = *(const u32x2*)(p0);
            u32x2 d01 = *(const u32x2*)(p0 + 32);        // col+1 (+128 B)
            u32x2 d10 = *(const u32x2*)(p0 + 4096);      // row+1
            u32x2 d11 = *(const u32x2*)(p0 + 4128);      // row+1, col+1
            u32x2 pkv;
#pragma unroll
            for (int j = 0; j < 2; ++j) {
                float v0 = w00 * bflo(d00[j]) + w01 * bflo(d01[j])
                         + w10 * bflo(d10[j]) + w11 * bflo(d11[j]);
                float v1 = w00 * bfhi(d00[j]) + w01 * bfhi(d01[j])
                         + w10 * bfhi(d10[j]) + w11 * bfhi(d11[j]);
                unsigned pk;
                asm("v_cvt_pk_bf16_f32 %0, %1, %2" : "=v"(pk) : "v"(v0), "v"(v1));
                pkv[j] = pk;
            }
            *(u32x2*)&sAd[px * 100 + kkl * 32 + cl2 * 2] = pkv;
        }
        __syncthreads();
#pragma unroll
        for (int ks = 0; ks < 6; ++ks) {
            int kk = ck * 3 + (ks >> 1);
            bf16x8 bfr = *(const bf16x8*)&dwT[((size_t)o_dw * 9 + kk) * 64
                                              + (ks & 1) * 32 + quad * 8];
#pragma unroll
            for (int mt = 0; mt < 4; ++mt) {
                bf16x8 a = *(const bf16x8*)&sA[(mt * 16 + l15) * KP
                                               + ks * 32 + quad * 8];
                acc[mt] = __builtin_amdgcn_mfma_f32_16x16x32_bf16(a, bfr, acc[mt], 0, 0, 0);
            }
        }
        __syncthreads();
    }

    // ================= Phase 4: store conv + stats partials =================
#pragma unroll
    for (int mt = 0; mt < 4; ++mt) {
        size_t idx = ((size_t)b * On + o_dw) * HW + (size_t)h * Ww + px0 + mt * 16 + quad * 4;
        *(f32x4*)(conv + idx) = acc[mt];
    }
    float s1 = 0.0f, s2 = 0.0f;
#pragma unroll
    for (int mt = 0; mt < 4; ++mt) {
#pragma unroll
        for (int r = 0; r < 4; ++r) {
            float v = acc[mt][r];
            s1 += v;
            s2 += v * v;
        }
    }
    s1 += __shfl_down(s1, 32, 64);  s2 += __shfl_down(s2, 32, 64);
    s1 += __shfl_down(s1, 16, 64);  s2 += __shfl_down(s2, 16, 64);
    if (lane < 16) {
        part[(size_t)o_dw * NBLK + blk]        = s1;
        part[(size_t)(64 + o_dw) * NBLK + blk] = s2;
    }
}

// ---------------------------------------------------------------------------
// Fused BN stats + apply + ReLU.
// Grid 1024: o = idx&63, bq = idx>>6. Each block re-reduces its channel's
// part rows (8 KB, L2-hit) -> sc/sh, then applies BN+ReLU over a 4096-float
// slab of conv.
// ---------------------------------------------------------------------------
__global__ __launch_bounds__(256) void bnstats_k(
    const float* __restrict__ part, const float* __restrict__ gamma,
    const float* __restrict__ beta, const float* __restrict__ conv,
    float* __restrict__ out)
{
    int idx = blockIdx.x;
    int o  = idx & 63;
    int bq = idx >> 6;          // b = bq>>2, q = bq&3
    int t = threadIdx.x;
    float s1 = 0.0f, s2 = 0.0f;
#pragma unroll
    for (int i = 0; i < NBLK / 256; ++i) {
        int j = t + 256 * i;
        s1 += part[(size_t)o * NBLK + j];
        s2 += part[(size_t)(64 + o) * NBLK + j];
    }
#pragma unroll
    for (int off = 32; off > 0; off >>= 1) {
        s1 += __shfl_down(s1, off, 64);
        s2 += __shfl_down(s2, off, 64);
    }
    __shared__ float r1[4], r2[4];
    __shared__ float sc_s, sh_s;
    if ((t & 63) == 0) { r1[t >> 6] = s1; r2[t >> 6] = s2; }
    __syncthreads();
    if (t == 0) {
        float S1 = r1[0] + r1[1] + r1[2] + r1[3];
        float S2 = r2[0] + r2[1] + r2[2] + r2[3];
        float n = (float)(Bn * HW);
        float mu = S1 / n;
        float var = S2 / n - mu * mu;
        float sc = gamma[o] * rsqrtf(var + 1e-5f);
        sc_s = sc;
        sh_s = beta[o] - mu * sc;
    }
    __syncthreads();
    float sc = sc_s, sh = sh_s;
    size_t base = (((size_t)(bq >> 2) * On + o) * HW + (size_t)(bq & 3) * 4096) / 4;
    const float4* cv = (const float4*)conv + base;
    float4* ov = (float4*)out + base;
#pragma unroll
    for (int i = 0; i < 4; ++i) {
        float4 v = cv[t + 256 * i];
        v.x = fmaxf(v.x * sc + sh, 0.0f);
        v.y = fmaxf(v.y * sc + sh, 0.0f);
        v.z = fmaxf(v.z * sc + sh, 0.0f);
        v.w = fmaxf(v.w * sc + sh, 0.0f);
        ov[t + 256 * i] = v;
    }
}

// ---------------------------------------------------------------------------
extern "C" void kernel_launch(void* const* d_in, const int* in_sizes, int n_in,
                              void* d_out, int out_size, void* d_ws, size_t ws_size,
                              hipStream_t stream)
{
    const float* x     = (const float*)d_in[0];
    const float* ow    = (const float*)d_in[1];
    const float* ob    = (const float*)d_in[2];
    const float* dw    = (const float*)d_in[3];
    // d_in[4] = dcn_b: cancels exactly under BN mean subtraction -> unused
    const float* gamma = (const float*)d_in[5];
    const float* beta  = (const float*)d_in[6];

    char* wsb = (char*)d_ws;
    unsigned* xtb = (unsigned*)wsb;
    float* conv = (float*)(wsb + XTB_BYTES);
    float* part = (float*)(wsb + XTB_BYTES + CONV_BYTES);
    short* owT  = (short*)(wsb + XTB_BYTES + CONV_BYTES + PART_BYTES + 512);
    short* dwT  = owT + 288 * 64;

    prep_k     <<<dim3(728),  dim3(256), 0, stream>>>(x, ow, dw, xtb, owT, dwT);
    dcn_fused_k<<<dim3(NBLK), dim3(256), 0, stream>>>(xtb, owT, ob, dwT, conv, part);
    bnstats_k  <<<dim3(1024), dim3(256), 0, stream>>>(part, gamma, beta, conv, (float*)d_out);
}